// Round 3
// baseline (406.552 us; speedup 1.0000x reference)
//
#include <hip/hip_runtime.h>
#include <hip/hip_bf16.h>
#include <math.h>

#define Bn 2
#define Cn 256
#define Nn 13824
#define NHn 4
#define Pn 64
#define Gn 8
#define NCH 54      // Nn/256

typedef __bf16 bf16x8 __attribute__((ext_vector_type(8)));
typedef unsigned short us8v __attribute__((ext_vector_type(8)));
typedef unsigned short us4v __attribute__((ext_vector_type(4)));
typedef float f32x4 __attribute__((ext_vector_type(4)));

__device__ __forceinline__ unsigned short f2bf(float f) {
  __hip_bfloat16 h = __float2bfloat16(f);
  return __builtin_bit_cast(unsigned short, h);
}
__device__ __forceinline__ float bf2f(unsigned short u) {
  return __builtin_bit_cast(float, ((unsigned)u) << 16);
}
__device__ __forceinline__ unsigned pk2(float a, float b) {
  return (unsigned)f2bf(a) | ((unsigned)f2bf(b) << 16);
}

// ---------------- pos transpose [N,C] -> [C,N] ----------------
__global__ __launch_bounds__(256) void k_transpose_pos(const float* __restrict__ pos,
                                                       float* __restrict__ posT) {
  __shared__ float tile[64][65];
  int n0 = blockIdx.x * 64;
  int c0 = blockIdx.y * 64;
  int tc = threadIdx.x & 63;
  int tr = threadIdx.x >> 6;
  #pragma unroll
  for (int k = 0; k < 16; k++) {
    int n = tr + k * 4;
    tile[n][tc] = pos[(size_t)(n0 + n) * Cn + c0 + tc];
  }
  __syncthreads();
  #pragma unroll
  for (int k = 0; k < 16; k++) {
    int c = tr + k * 4;
    posT[(size_t)(c0 + c) * Nn + n0 + tc] = tile[tc][c];
  }
}

// ---------------- weight convert: wqT[j][c], w1T[j][c] (bf16) ----------------
__global__ __launch_bounds__(256) void k_wcvt(const float* __restrict__ wqkv,
                                              const float* __restrict__ w1,
                                              unsigned short* __restrict__ wqT,
                                              unsigned short* __restrict__ w1T) {
  int j = blockIdx.x, c = threadIdx.x;
  if (j < 256) wqT[(size_t)j * 256 + c] = f2bf(wqkv[(size_t)c * 768 + j]);
  else w1T[(size_t)(j - 256) * 256 + c] = f2bf(w1[(size_t)c * 128 + (j - 256)]);
}

// ---------------- w_e transpose: weT[p][n] bf16 ----------------
__global__ __launch_bounds__(256) void k_wet(const float* __restrict__ we,
                                             unsigned short* __restrict__ weT) {
  __shared__ float tile[64][65];
  int n0 = blockIdx.x * 64;
  int tc = threadIdx.x & 63;
  int tr = threadIdx.x >> 6;
  #pragma unroll
  for (int k = 0; k < 16; k++) {
    int n = tr + k * 4;
    tile[n][tc] = we[(size_t)(n0 + n) * Pn + tc];
  }
  __syncthreads();
  #pragma unroll
  for (int k = 0; k < 16; k++) {
    int p = tr + k * 4;
    weT[(size_t)p * Nn + n0 + tc] = f2bf(tile[tc][p]);
  }
}

// ---------------- grouped 1x1x1 conv + fused instance-norm stat partials -----
template <bool NORM>
__global__ __launch_bounds__(256) void k_gconv(const float* __restrict__ src,
                                               const float* __restrict__ wt,
                                               const float* __restrict__ bias,
                                               const float* __restrict__ stats,
                                               float* __restrict__ dst,
                                               float* __restrict__ statacc) {
  int chunk = blockIdx.x, g = blockIdx.y, b = blockIdx.z;
  int t = threadIdx.x;
  int n = chunk * 256 + t;
  __shared__ float ws_[32][32];
  __shared__ float ms[32], rs[32], bs[32];
  __shared__ float sred[4][32][2];
  #pragma unroll
  for (int i = 0; i < 4; i++) {
    int e = t + 256 * i;
    ws_[e >> 5][e & 31] = wt[g * 1024 + e];
  }
  if (t < 32) {
    bs[t] = bias[g * 32 + t];
    if (NORM) {
      ms[t] = stats[(b * Cn + g * 32 + t) * 2 + 0];
      rs[t] = stats[(b * Cn + g * 32 + t) * 2 + 1];
    }
  }
  __syncthreads();
  float in[32];
  const float* sp = src + ((size_t)b * Cn + g * 32) * Nn + n;
  #pragma unroll
  for (int i = 0; i < 32; i++) {
    float v = sp[(size_t)i * Nn];
    if (NORM) {
      v = (v - ms[i]) * rs[i];
      v = v >= 0.f ? v : 0.01f * v;
    }
    in[i] = v;
  }
  int w = t >> 6, lane = t & 63;
  float* dp = dst + ((size_t)b * Cn + g * 32) * Nn + n;
  #pragma unroll
  for (int o = 0; o < 32; o++) {
    float acc = bs[o];
    #pragma unroll
    for (int i = 0; i < 32; i++) acc = fmaf(in[i], ws_[i][o], acc);
    dp[(size_t)o * Nn] = acc;
    float a = acc, a2 = acc * acc;
    #pragma unroll
    for (int off = 1; off < 64; off <<= 1) {
      a += __shfl_xor(a, off);
      a2 += __shfl_xor(a2, off);
    }
    if (lane == 0) { sred[w][o][0] = a; sred[w][o][1] = a2; }
  }
  __syncthreads();
  if (t < 64) {
    int o = t & 31, st = t >> 5;
    float v = sred[0][o][st] + sred[1][o][st] + sred[2][o][st] + sred[3][o][st];
    atomicAdd(&statacc[(b * Cn + g * 32 + o) * 2 + st], v);
  }
}

// ---------------- stats finalize: sums -> mean/rstd ----------------
__global__ __launch_bounds__(256) void k_statfin(const float* __restrict__ acc,
                                                 float* __restrict__ stats) {
  int r = blockIdx.x * 256 + threadIdx.x;  // 512 rows
  float s = acc[r * 2], ss = acc[r * 2 + 1];
  float m = s * (1.f / Nn);
  float var = ss * (1.f / Nn) - m * m;
  stats[r * 2 + 0] = m;
  stats[r * 2 + 1] = rsqrtf(var + 1e-5f);
}

// ---------------- fused: resid + tokenstats + LN-apply (both paths) ----------
// out: xnTbf bf16 [b][c][n], xnbf bf16 [b][n][c], xcnbf bf16 [b][n][c],
//      pooledacc[b][c] += sum_n xc_n * wpool[n]
__global__ __launch_bounds__(256) void k_fused_ln(
    const float* __restrict__ x, const float* __restrict__ t3,
    const float* __restrict__ posT, const float* __restrict__ stats3,
    const float* __restrict__ g, const float* __restrict__ beta,
    const float* __restrict__ wpool,
    unsigned short* __restrict__ xnbf, unsigned short* __restrict__ xnTbf,
    unsigned short* __restrict__ xcnbf, float* __restrict__ pooledacc) {
  int b = blockIdx.y, n0 = blockIdx.x * 32;
  int t = threadIdx.x, tg = t & 7, cg = t >> 3;   // cg 0..31
  int tok4 = tg * 4;
  __shared__ float vbuf[32 * 256];
  __shared__ float v2buf[32 * 256];
  __shared__ float red[4][8][4][4];
  __shared__ float tms[32][4];
  __shared__ float gb[256], bb[256], s3m[256], s3r[256];
  __shared__ float wp[32];
  __shared__ unsigned short Tb[2][32][36];

  gb[t] = g[t]; bb[t] = beta[t];
  s3m[t] = stats3[(b * Cn + t) * 2 + 0];
  s3r[t] = stats3[(b * Cn + t) * 2 + 1];
  if (t < 32) wp[t] = wpool[n0 + t];
  __syncthreads();

  float s1[4] = {}, q1[4] = {}, s2[4] = {}, q2[4] = {};
  #pragma unroll
  for (int ci = 0; ci < 8; ci++) {
    int c = ci * 32 + cg;
    f32x4 xv = *(const f32x4*)(x + ((size_t)b * Cn + c) * Nn + n0 + tok4);
    f32x4 pv = *(const f32x4*)(posT + (size_t)c * Nn + n0 + tok4);
    f32x4 tv = *(const f32x4*)(t3 + ((size_t)b * Cn + c) * Nn + n0 + tok4);
    float m3 = s3m[c], r3 = s3r[c];
    #pragma unroll
    for (int j = 0; j < 4; j++) {
      float v = xv[j] + pv[j];
      vbuf[(ci * 4 + j) * 256 + t] = v;
      s1[j] += v; q1[j] += v * v;
      float xcv = (tv[j] - m3) * r3 + xv[j];
      xcv = xcv >= 0.f ? xcv : 0.01f * xcv;
      float v2 = xcv + pv[j];
      v2buf[(ci * 4 + j) * 256 + t] = v2;
      s2[j] += v2; q2[j] += v2 * v2;
    }
  }
  // reduce over cg: wave-local xor 8/16/32 then cross-wave via LDS
  #pragma unroll
  for (int j = 0; j < 4; j++) {
    float a = s1[j], bq = q1[j], c2 = s2[j], d2 = q2[j];
    #pragma unroll
    for (int off = 8; off < 64; off <<= 1) {
      a += __shfl_xor(a, off);
      bq += __shfl_xor(bq, off);
      c2 += __shfl_xor(c2, off);
      d2 += __shfl_xor(d2, off);
    }
    if ((t & 63) < 8) {
      int w = t >> 6, tgg = t & 7;
      red[w][tgg][j][0] = a; red[w][tgg][j][1] = bq;
      red[w][tgg][j][2] = c2; red[w][tgg][j][3] = d2;
    }
  }
  __syncthreads();
  if (t < 32) {
    int tgg = t >> 2, j = t & 3;
    float a = 0, bq = 0, c2 = 0, d2 = 0;
    #pragma unroll
    for (int w = 0; w < 4; w++) {
      a += red[w][tgg][j][0]; bq += red[w][tgg][j][1];
      c2 += red[w][tgg][j][2]; d2 += red[w][tgg][j][3];
    }
    float m1 = a * (1.f / 256.f);
    float r1 = rsqrtf(bq * (1.f / 256.f) - m1 * m1 + 1e-5f);
    float m2 = c2 * (1.f / 256.f);
    float r2 = rsqrtf(d2 * (1.f / 256.f) - m2 * m2 + 1e-5f);
    tms[t][0] = m1; tms[t][1] = r1; tms[t][2] = m2; tms[t][3] = r2;
  }
  __syncthreads();
  float m1v[4], r1v[4], m2v[4], r2v[4];
  #pragma unroll
  for (int j = 0; j < 4; j++) {
    m1v[j] = tms[tok4 + j][0]; r1v[j] = tms[tok4 + j][1];
    m2v[j] = tms[tok4 + j][2]; r2v[j] = tms[tok4 + j][3];
  }
  int row = t >> 3, seg = t & 7;
  // ---- phase 1 apply: x_n ----
  #pragma unroll
  for (int ci = 0; ci < 8; ci++) {
    int c = ci * 32 + cg;
    float gg = gb[c], bv = bb[c];
    us4v o4;
    #pragma unroll
    for (int j = 0; j < 4; j++) {
      float v = vbuf[(ci * 4 + j) * 256 + t];
      o4[j] = f2bf((v - m1v[j]) * r1v[j] * gg + bv);
    }
    *(us4v*)(xnTbf + ((size_t)b * Cn + c) * Nn + n0 + tok4) = o4;
    #pragma unroll
    for (int j = 0; j < 4; j++) Tb[ci & 1][tok4 + j][cg] = o4[j];
    __syncthreads();
    *(us4v*)(xnbf + ((size_t)b * Nn + n0 + row) * Cn + ci * 32 + seg * 4) =
        *(const us4v*)&Tb[ci & 1][row][seg * 4];
  }
  // ---- phase 2 apply: xc_n + pooled partial ----
  #pragma unroll
  for (int ci = 0; ci < 8; ci++) {
    int c = ci * 32 + cg;
    float gg = gb[c], bv = bb[c];
    us4v o4;
    float pp = 0.f;
    #pragma unroll
    for (int j = 0; j < 4; j++) {
      float v = v2buf[(ci * 4 + j) * 256 + t];
      float o = (v - m2v[j]) * r2v[j] * gg + bv;
      o4[j] = f2bf(o);
      pp = fmaf(o, wp[tok4 + j], pp);
    }
    #pragma unroll
    for (int j = 0; j < 4; j++) Tb[ci & 1][tok4 + j][cg] = o4[j];
    pp += __shfl_xor(pp, 1);
    pp += __shfl_xor(pp, 2);
    pp += __shfl_xor(pp, 4);
    __syncthreads();
    *(us4v*)(xcnbf + ((size_t)b * Nn + n0 + row) * Cn + ci * 32 + seg * 4) =
        *(const us4v*)&Tb[ci & 1][row][seg * 4];
    if (tg == 0) atomicAdd(&pooledacc[b * Cn + c], pp);
  }
}

// ---------------- Q GEMM (bf16 MFMA): out q_bf [n][256] + qsq ----------------
__global__ __launch_bounds__(256) void k_gemm_q(
    const unsigned short* __restrict__ Aw,   // wqT [256][256]
    const unsigned short* __restrict__ Bx,   // xnbf [b][n][256]
    unsigned short* __restrict__ qo,         // [b][n][256]
    float* __restrict__ qsq) {
  __shared__ char lds[24576];
  int b = blockIdx.z, n0 = blockIdx.x * 128, j0 = blockIdx.y * 64;
  int t = threadIdx.x, lane = t & 63, wid = t >> 6;
  int wj = wid >> 1, wt = wid & 1;
  f32x4 acc[2][4];
  #pragma unroll
  for (int i = 0; i < 2; i++)
    #pragma unroll
    for (int j = 0; j < 4; j++) acc[i][j] = (f32x4){0.f, 0.f, 0.f, 0.f};
  for (int k0 = 0; k0 < 256; k0 += 64) {
    {
      int r = t >> 2, off = (t & 3) * 16;
      const unsigned short* ga = Aw + (size_t)(j0 + r) * 256 + k0 + off;
      #pragma unroll
      for (int i = 0; i < 2; i++)
        *(us8v*)(lds + r * 128 + ((off * 2 + 16 * i) ^ ((r & 7) << 4))) = *(const us8v*)(ga + i * 8);
      int rb = t >> 1, offb = (t & 1) * 32;
      const unsigned short* gb = Bx + ((size_t)b * Nn + n0 + rb) * 256 + k0 + offb;
      #pragma unroll
      for (int i = 0; i < 4; i++)
        *(us8v*)(lds + 8192 + rb * 128 + ((offb * 2 + 16 * i) ^ ((rb & 7) << 4))) = *(const us8v*)(gb + i * 8);
    }
    __syncthreads();
    #pragma unroll
    for (int ks = 0; ks < 2; ks++) {
      int kb = ks * 64 + (lane >> 4) * 16;
      bf16x8 af[2], bfr[4];
      #pragma unroll
      for (int mt = 0; mt < 2; mt++) {
        int row = wj * 32 + mt * 16 + (lane & 15);
        af[mt] = *(bf16x8*)(lds + row * 128 + (kb ^ ((row & 7) << 4)));
      }
      #pragma unroll
      for (int tt = 0; tt < 4; tt++) {
        int row = wt * 64 + tt * 16 + (lane & 15);
        bfr[tt] = *(bf16x8*)(lds + 8192 + row * 128 + (kb ^ ((row & 7) << 4)));
      }
      #pragma unroll
      for (int mt = 0; mt < 2; mt++)
        #pragma unroll
        for (int tt = 0; tt < 4; tt++)
          acc[mt][tt] = __builtin_amdgcn_mfma_f32_16x16x32_bf16(af[mt], bfr[tt], acc[mt][tt], 0, 0, 0);
    }
    __syncthreads();
  }
  #pragma unroll
  for (int mt = 0; mt < 2; mt++)
    #pragma unroll
    for (int r = 0; r < 4; r++) {
      float v = 0.f;
      #pragma unroll
      for (int tt = 0; tt < 4; tt++) { float e = acc[mt][tt][r]; v = fmaf(e, e, v); }
      #pragma unroll
      for (int m = 1; m < 16; m <<= 1) v += __shfl_xor(v, m);
      if ((lane & 15) == 0)
        atomicAdd(&qsq[b * Cn + j0 + wj * 32 + mt * 16 + (lane >> 4) * 4 + r], v);
    }
  unsigned short* O = (unsigned short*)lds;  // [128][72]
  #pragma unroll
  for (int mt = 0; mt < 2; mt++)
    #pragma unroll
    for (int tt = 0; tt < 4; tt++) {
      int tok = wt * 64 + tt * 16 + (lane & 15);
      int jb = wj * 32 + mt * 16 + ((lane >> 4) << 2);
      uint2 v;
      v.x = pk2(acc[mt][tt][0], acc[mt][tt][1]);
      v.y = pk2(acc[mt][tt][2], acc[mt][tt][3]);
      *(uint2*)(O + tok * 72 + jb) = v;
    }
  __syncthreads();
  int tok = t >> 1, js = (t & 1) * 32;
  unsigned short* dst = qo + ((size_t)b * Nn + n0 + tok) * 256 + j0 + js;
  #pragma unroll
  for (int i = 0; i < 4; i++) *(us8v*)(dst + i * 8) = *(const us8v*)(O + tok * 72 + js + i * 8);
}

// ---------------- xe (bf16 MFMA split-K): part[b,ch][c][p] ----------------
__global__ __launch_bounds__(256) void k_xe(const unsigned short* __restrict__ xnT,
                                            const unsigned short* __restrict__ weT,
                                            float* __restrict__ part) {
  __shared__ char lds[16384];
  int chunk = blockIdx.x, ct = blockIdx.y, b = blockIdx.z;
  int c0 = ct * 64, nb = chunk * 256;
  int t = threadIdx.x, lane = t & 63, wid = t >> 6;
  f32x4 acc4[4];
  #pragma unroll
  for (int i = 0; i < 4; i++) acc4[i] = (f32x4){0.f, 0.f, 0.f, 0.f};
  for (int k0 = 0; k0 < 256; k0 += 64) {
    int r = t >> 2, off = (t & 3) * 16;
    const unsigned short* ga = xnT + ((size_t)b * Cn + c0 + r) * Nn + nb + k0 + off;
    const unsigned short* gb = weT + (size_t)r * Nn + nb + k0 + off;
    #pragma unroll
    for (int i = 0; i < 2; i++) {
      *(us8v*)(lds + r * 128 + ((off * 2 + 16 * i) ^ ((r & 7) << 4))) = *(const us8v*)(ga + i * 8);
      *(us8v*)(lds + 8192 + r * 128 + ((off * 2 + 16 * i) ^ ((r & 7) << 4))) = *(const us8v*)(gb + i * 8);
    }
    __syncthreads();
    #pragma unroll
    for (int ks = 0; ks < 2; ks++) {
      int kb = ks * 64 + (lane >> 4) * 16;
      int rowa = wid * 16 + (lane & 15);
      bf16x8 a = *(bf16x8*)(lds + rowa * 128 + (kb ^ ((rowa & 7) << 4)));
      #pragma unroll
      for (int pt = 0; pt < 4; pt++) {
        int rowb = pt * 16 + (lane & 15);
        bf16x8 bv = *(bf16x8*)(lds + 8192 + rowb * 128 + (kb ^ ((rowb & 7) << 4)));
        acc4[pt] = __builtin_amdgcn_mfma_f32_16x16x32_bf16(a, bv, acc4[pt], 0, 0, 0);
      }
    }
    __syncthreads();
  }
  size_t base = ((size_t)(b * NCH + chunk)) * (Cn * Pn);
  #pragma unroll
  for (int pt = 0; pt < 4; pt++)
    #pragma unroll
    for (int r = 0; r < 4; r++) {
      int c = c0 + wid * 16 + (lane >> 4) * 4 + r;
      int p = pt * 16 + (lane & 15);
      part[base + (size_t)c * Pn + p] = acc4[pt][r];
    }
}

__global__ __launch_bounds__(256) void k_xe_reduce(const float* __restrict__ part,
                                                   float* __restrict__ xe) {
  int i = blockIdx.x * 256 + threadIdx.x;     // B*C*P = 32768
  int b = i / (Cn * Pn);
  int cp = i % (Cn * Pn);
  float s = 0.f;
  for (int ch = 0; ch < NCH; ch++) s += part[(size_t)(b * NCH + ch) * Cn * Pn + cp];
  xe[i] = s;
}

// ---------------- kv proj -> kpT (scale*T folded, [b][h][p][d]) / vp [b][h][d][p]
__global__ __launch_bounds__(256) void k_kvproj(const float* __restrict__ xe,
                                                const float* __restrict__ wqkv,
                                                const float* __restrict__ be,
                                                const float* __restrict__ qsq,
                                                const float* __restrict__ temp,
                                                unsigned short* __restrict__ kvp) {
  int hd = blockIdx.x * 4 + (threadIdx.x >> 6);
  int kv = blockIdx.y, b = blockIdx.z;
  int p = threadIdx.x & 63;
  int col = (kv + 1) * Cn + hd;
  float acc = be[p];
  for (int c = 0; c < Cn; c++)
    acc = fmaf(xe[((size_t)b * Cn + c) * Pn + p], wqkv[(size_t)c * 768 + col], acc);
  int h = hd >> 6, d = hd & 63;
  if (kv == 0) {
    float sc = 1.f / fmaxf(sqrtf(qsq[b * Cn + hd]), 1e-12f);
    acc *= sc * temp[h];
    kvp[((size_t)(b * 4 + h)) * 4096 + p * 64 + d] = f2bf(acc);
  } else {
    kvp[32768 + ((size_t)(b * 4 + h)) * 4096 + d * 64 + p] = f2bf(acc);
  }
}

// ---------------- gate = sigmoid(relu(pooled @ wfc1) @ wfc2) ----------------
__global__ __launch_bounds__(256) void k_gate(const float* __restrict__ pooledacc,
                                              const float* __restrict__ bpool,
                                              const float* __restrict__ wfc1,
                                              const float* __restrict__ wfc2,
                                              float* __restrict__ gate) {
  int b = blockIdx.x, t = threadIdx.x;
  __shared__ float pl[256], h1[64];
  pl[t] = pooledacc[b * Cn + t] + bpool[0];
  __syncthreads();
  if (t < 64) {
    float a = 0.f;
    for (int c = 0; c < Cn; c++) a = fmaf(pl[c], wfc1[c * 64 + t], a);
    h1[t] = fmaxf(a, 0.f);
  }
  __syncthreads();
  float a = 0.f;
  for (int j = 0; j < 64; j++) a = fmaf(h1[j], wfc2[j * Cn + t], a);
  gate[b * Cn + t] = 1.f / (1.f + __expf(-a));
}

// ---------------- w2gT[b][j][c] = gate[b][c]*w_out2[c][j] (bf16) -------------
__global__ __launch_bounds__(256) void k_w2gT(const float* __restrict__ gate,
                                              const float* __restrict__ w2,
                                              unsigned short* __restrict__ w2gT) {
  int j = blockIdx.x, b = blockIdx.y, c = threadIdx.x;
  w2gT[((size_t)b * 128 + j) * 256 + c] = f2bf(gate[b * Cn + c] * w2[(size_t)c * 128 + j]);
}

// ---------------- attention (bf16 MFMA, P=64, per-token softmax) -------------
__global__ __launch_bounds__(128) void k_attn(const unsigned short* __restrict__ qbf,
                                              const unsigned short* __restrict__ kvp,
                                              unsigned short* __restrict__ xsa) {
  __shared__ char lds[16384 + 2 * 9216];
  int nb = blockIdx.x, h = blockIdx.y, b = blockIdx.z;
  int t = threadIdx.x, lane = t & 63, w = t >> 6;
  char* kpT = lds;
  char* vp = lds + 8192;
  unsigned short* P = (unsigned short*)(lds + 16384 + w * 9216);
  const unsigned short* kg = kvp + ((size_t)(b * 4 + h)) * 4096;
  const unsigned short* vg = kvp + 32768 + ((size_t)(b * 4 + h)) * 4096;
  {
    int r = t >> 1, off = (t & 1) * 32;
    #pragma unroll
    for (int i = 0; i < 4; i++) {
      *(us8v*)(kpT + r * 128 + ((off * 2 + 16 * i) ^ ((r & 7) << 4))) = *(const us8v*)(kg + r * 64 + off + i * 8);
      *(us8v*)(vp + r * 128 + ((off * 2 + 16 * i) ^ ((r & 7) << 4))) = *(const us8v*)(vg + r * 64 + off + i * 8);
    }
  }
  __syncthreads();
  int n0 = nb * 128 + w * 64;
  bf16x8 qf[4][2];
  #pragma unroll
  for (int tt = 0; tt < 4; tt++)
    #pragma unroll
    for (int ks = 0; ks < 2; ks++) {
      int n = n0 + tt * 16 + (lane & 15);
      qf[tt][ks] = *(const bf16x8*)(qbf + ((size_t)b * Nn + n) * 256 + h * 64 + ks * 32 + (lane >> 4) * 8);
    }
  f32x4 s[4][4];
  #pragma unroll
  for (int i = 0; i < 4; i++)
    #pragma unroll
    for (int j = 0; j < 4; j++) s[i][j] = (f32x4){0.f, 0.f, 0.f, 0.f};
  #pragma unroll
  for (int ks = 0; ks < 2; ks++) {
    int kb = ks * 64 + (lane >> 4) * 16;
    #pragma unroll
    for (int mt = 0; mt < 4; mt++) {
      int row = mt * 16 + (lane & 15);
      bf16x8 a = *(bf16x8*)(kpT + row * 128 + (kb ^ ((row & 7) << 4)));
      #pragma unroll
      for (int tt = 0; tt < 4; tt++)
        s[mt][tt] = __builtin_amdgcn_mfma_f32_16x16x32_bf16(a, qf[tt][ks], s[mt][tt], 0, 0, 0);
    }
  }
  #pragma unroll
  for (int tt = 0; tt < 4; tt++) {
    float mx = -1e30f;
    #pragma unroll
    for (int mt = 0; mt < 4; mt++)
      #pragma unroll
      for (int r = 0; r < 4; r++) mx = fmaxf(mx, s[mt][tt][r]);
    mx = fmaxf(mx, __shfl_xor(mx, 16));
    mx = fmaxf(mx, __shfl_xor(mx, 32));
    float den = 0.f;
    #pragma unroll
    for (int mt = 0; mt < 4; mt++)
      #pragma unroll
      for (int r = 0; r < 4; r++) {
        float e = __expf(s[mt][tt][r] - mx);
        s[mt][tt][r] = e; den += e;
      }
    den += __shfl_xor(den, 16);
    den += __shfl_xor(den, 32);
    float inv = 1.f / den;
    #pragma unroll
    for (int mt = 0; mt < 4; mt++)
      #pragma unroll
      for (int r = 0; r < 4; r++) s[mt][tt][r] *= inv;
  }
  #pragma unroll
  for (int mt = 0; mt < 4; mt++)
    #pragma unroll
    for (int tt = 0; tt < 4; tt++) {
      int tok = tt * 16 + (lane & 15);
      int pb = mt * 16 + ((lane >> 4) << 2);
      uint2 v;
      v.x = pk2(s[mt][tt][0], s[mt][tt][1]);
      v.y = pk2(s[mt][tt][2], s[mt][tt][3]);
      *(uint2*)(P + tok * 72 + pb) = v;
    }
  bf16x8 pf[4][2];
  #pragma unroll
  for (int mt = 0; mt < 4; mt++)
    #pragma unroll
    for (int ks = 0; ks < 2; ks++)
      pf[mt][ks] = *(const bf16x8*)(P + (mt * 16 + (lane & 15)) * 72 + ks * 32 + (lane >> 4) * 8);
  f32x4 o[4][4];
  #pragma unroll
  for (int i = 0; i < 4; i++)
    #pragma unroll
    for (int j = 0; j < 4; j++) o[i][j] = (f32x4){0.f, 0.f, 0.f, 0.f};
  #pragma unroll
  for (int ks = 0; ks < 2; ks++) {
    int kb = ks * 64 + (lane >> 4) * 16;
    #pragma unroll
    for (int nt = 0; nt < 4; nt++) {
      int row = nt * 16 + (lane & 15);
      bf16x8 bfv = *(bf16x8*)(vp + row * 128 + (kb ^ ((row & 7) << 4)));
      #pragma unroll
      for (int mt = 0; mt < 4; mt++)
        o[mt][nt] = __builtin_amdgcn_mfma_f32_16x16x32_bf16(pf[mt][ks], bfv, o[mt][nt], 0, 0, 0);
    }
  }
  #pragma unroll
  for (int mt = 0; mt < 4; mt++)
    #pragma unroll
    for (int nt = 0; nt < 4; nt++) {
      int d = nt * 16 + (lane & 15);
      int tb = mt * 16 + ((lane >> 4) << 2);
      uint2 v;
      v.x = pk2(o[mt][nt][0], o[mt][nt][1]);
      v.y = pk2(o[mt][nt][2], o[mt][nt][3]);
      *(uint2*)(P + d * 72 + tb) = v;
    }
  size_t fb = (size_t)b * Cn * Nn + ((size_t)(lane * 4 + h)) * Nn + n0;
  #pragma unroll
  for (int k = 0; k < 8; k++)
    *(us8v*)(xsa + fb + k * 8) = *(const us8v*)(P + lane * 72 + k * 8);
}

// ---------------- out GEMM (bf16 MFMA) + fused epilogue (bf16 x_n) -----------
__global__ __launch_bounds__(256) void k_gemm_out(
    const unsigned short* __restrict__ Aw, size_t a_bstride,
    const unsigned short* __restrict__ Bx,
    const float* __restrict__ bias, int cbase,
    const unsigned short* __restrict__ xnT, const float* __restrict__ gamma,
    float* __restrict__ outp) {
  __shared__ char lds[33792];
  int b = blockIdx.z, n0 = blockIdx.x * 128, j0 = blockIdx.y * 64;
  int t = threadIdx.x, lane = t & 63, wid = t >> 6;
  int wj = wid >> 1, wt = wid & 1;
  const unsigned short* Ab = Aw + a_bstride * b;
  f32x4 acc[2][4];
  #pragma unroll
  for (int i = 0; i < 2; i++)
    #pragma unroll
    for (int j = 0; j < 4; j++) acc[i][j] = (f32x4){0.f, 0.f, 0.f, 0.f};
  for (int k0 = 0; k0 < 256; k0 += 64) {
    {
      int r = t >> 2, off = (t & 3) * 16;
      const unsigned short* ga = Ab + (size_t)(j0 + r) * 256 + k0 + off;
      #pragma unroll
      for (int i = 0; i < 2; i++)
        *(us8v*)(lds + r * 128 + ((off * 2 + 16 * i) ^ ((r & 7) << 4))) = *(const us8v*)(ga + i * 8);
      int rb = t >> 1, offb = (t & 1) * 32;
      const unsigned short* gb = Bx + ((size_t)b * Nn + n0 + rb) * 256 + k0 + offb;
      #pragma unroll
      for (int i = 0; i < 4; i++)
        *(us8v*)(lds + 8192 + rb * 128 + ((offb * 2 + 16 * i) ^ ((rb & 7) << 4))) = *(const us8v*)(gb + i * 8);
    }
    __syncthreads();
    #pragma unroll
    for (int ks = 0; ks < 2; ks++) {
      int kb = ks * 64 + (lane >> 4) * 16;
      bf16x8 af[2], bfr[4];
      #pragma unroll
      for (int mt = 0; mt < 2; mt++) {
        int row = wj * 32 + mt * 16 + (lane & 15);
        af[mt] = *(bf16x8*)(lds + row * 128 + (kb ^ ((row & 7) << 4)));
      }
      #pragma unroll
      for (int tt = 0; tt < 4; tt++) {
        int row = wt * 64 + tt * 16 + (lane & 15);
        bfr[tt] = *(bf16x8*)(lds + 8192 + row * 128 + (kb ^ ((row & 7) << 4)));
      }
      #pragma unroll
      for (int mt = 0; mt < 2; mt++)
        #pragma unroll
        for (int tt = 0; tt < 4; tt++)
          acc[mt][tt] = __builtin_amdgcn_mfma_f32_16x16x32_bf16(af[mt], bfr[tt], acc[mt][tt], 0, 0, 0);
    }
    __syncthreads();
  }
  float* OT = (float*)lds;  // [64 j][132 tok]
  #pragma unroll
  for (int mt = 0; mt < 2; mt++)
    #pragma unroll
    for (int tt = 0; tt < 4; tt++)
      #pragma unroll
      for (int r = 0; r < 4; r++) {
        int j = wj * 32 + mt * 16 + (lane >> 4) * 4 + r;
        int tok = wt * 64 + tt * 16 + (lane & 15);
        OT[j * 132 + tok] = acc[mt][tt][r];
      }
  __syncthreads();
  int jj = t >> 2, ts = (t & 3) * 32;
  int c = cbase + j0 + jj;
  float gm = gamma[c], bi = bias[j0 + jj];
  const unsigned short* xn = xnT + ((size_t)b * Cn + c) * Nn + n0 + ts;
  float* op = outp + ((size_t)b * Cn + c) * Nn + n0 + ts;
  #pragma unroll
  for (int i = 0; i < 8; i++) {
    f32x4 v = *(const f32x4*)(&OT[jj * 132 + ts + i * 4]);
    us4v xv = *(const us4v*)(xn + i * 4);
    f32x4 ov;
    #pragma unroll
    for (int e = 0; e < 4; e++) ov[e] = bf2f(xv[e]) + gm * (v[e] + bi);
    *(f32x4*)(op + i * 4) = ov;
  }
}

extern "C" void kernel_launch(void* const* d_in, const int* in_sizes, int n_in,
                              void* d_out, int out_size, void* d_ws, size_t ws_size,
                              hipStream_t stream) {
  const float* x      = (const float*)d_in[0];
  const float* pos    = (const float*)d_in[1];
  const float* ln_g   = (const float*)d_in[2];
  const float* ln_b   = (const float*)d_in[3];
  const float* gamma  = (const float*)d_in[4];
  const float* temp2  = (const float*)d_in[5];
  const float* w_qkv  = (const float*)d_in[6];
  const float* w_e    = (const float*)d_in[7];
  const float* b_e    = (const float*)d_in[8];
  const float* w_pool = (const float*)d_in[9];
  const float* b_pool = (const float*)d_in[10];
  const float* w_fc1  = (const float*)d_in[11];
  const float* w_fc2  = (const float*)d_in[12];
  const float* w_out1 = (const float*)d_in[13];
  const float* b_out1 = (const float*)d_in[14];
  const float* w_out2 = (const float*)d_in[15];
  const float* b_out2 = (const float*)d_in[16];
  const float* w_c1   = (const float*)d_in[17];
  const float* b_c1   = (const float*)d_in[18];
  const float* w_c2   = (const float*)d_in[19];
  const float* b_c2   = (const float*)d_in[20];
  (void)in_sizes; (void)n_in; (void)out_size; (void)ws_size;
  float* out = (float*)d_out;

  const size_t SZ = (size_t)Bn * Cn * Nn;   // 7,077,888
  const size_t NC = (size_t)Nn * Cn;        // 3,538,944
  char* base = (char*)d_ws;
  size_t off = 0;
  auto alloc = [&](size_t bytes) { void* p = base + off; off += (bytes + 255) & ~(size_t)255; return p; };
  float* t3     = (float*)alloc(SZ * 4);
  char*  alias  = (char*)alloc(SZ * 4);     // t1 (early) == qbf + xsabf (late)
  float* posT   = (float*)alloc(NC * 4);
  float* xepart = (float*)alloc((size_t)NCH * Bn * Cn * Pn * 4);
  unsigned short* xnbf  = (unsigned short*)alloc(SZ * 2);
  unsigned short* xnTbf = (unsigned short*)alloc(SZ * 2);
  unsigned short* xcnbf = (unsigned short*)alloc(SZ * 2);
  unsigned short* weT   = (unsigned short*)alloc((size_t)Pn * Nn * 2);
  float* zeros  = (float*)alloc(3072 * 4);
  float* stats1acc = zeros;            // 1024
  float* stats3acc = zeros + 1024;     // 1024
  float* qsq       = zeros + 2048;     // 512
  float* pooledacc = zeros + 2560;     // 512
  float* stats1 = (float*)alloc(1024 * 4);
  float* stats3 = (float*)alloc(1024 * 4);
  float* xe     = (float*)alloc(32768 * 4);
  float* gateb  = (float*)alloc(512 * 4);
  unsigned short* kvp  = (unsigned short*)alloc(65536 * 2);
  unsigned short* w2gt = (unsigned short*)alloc(65536 * 2);
  unsigned short* wqT  = (unsigned short*)alloc(65536 * 2);
  unsigned short* w1T  = (unsigned short*)alloc(32768 * 2);

  float* t1 = (float*)alias;
  unsigned short* qbf   = (unsigned short*)alias;
  unsigned short* xsabf = (unsigned short*)alias + SZ;

  hipMemsetAsync(zeros, 0, 3072 * 4, stream);
  k_wcvt<<<dim3(384), 256, 0, stream>>>(w_qkv, w_out1, wqT, w1T);
  k_wet<<<dim3(216), 256, 0, stream>>>(w_e, weT);
  k_transpose_pos<<<dim3(216, 4), 256, 0, stream>>>(pos, posT);
  k_gconv<false><<<dim3(NCH, Gn, Bn), 256, 0, stream>>>(x, w_c1, b_c1, nullptr, t1, stats1acc);
  k_statfin<<<dim3(2), 256, 0, stream>>>(stats1acc, stats1);
  k_gconv<true><<<dim3(NCH, Gn, Bn), 256, 0, stream>>>(t1, w_c2, b_c2, stats1, t3, stats3acc);
  k_statfin<<<dim3(2), 256, 0, stream>>>(stats3acc, stats3);
  k_fused_ln<<<dim3(432, Bn), 256, 0, stream>>>(x, t3, posT, stats3, ln_g, ln_b, w_pool,
                                                xnbf, xnTbf, xcnbf, pooledacc);
  k_gemm_q<<<dim3(108, 4, Bn), 256, 0, stream>>>(wqT, xnbf, qbf, qsq);
  k_xe<<<dim3(NCH, 4, Bn), 256, 0, stream>>>(xnTbf, weT, xepart);
  k_xe_reduce<<<dim3(128), 256, 0, stream>>>(xepart, xe);
  k_kvproj<<<dim3(64, 2, Bn), 256, 0, stream>>>(xe, w_qkv, b_e, qsq, temp2, kvp);
  k_gate<<<dim3(Bn), 256, 0, stream>>>(pooledacc, b_pool, w_fc1, w_fc2, gateb);
  k_w2gT<<<dim3(128, Bn), 256, 0, stream>>>(gateb, w_out2, w2gt);
  k_attn<<<dim3(108, NHn, Bn), 128, 0, stream>>>(qbf, kvp, xsabf);
  k_gemm_out<<<dim3(108, 2, Bn), 256, 0, stream>>>(w1T, 0, xsabf, b_out1, 0, xnTbf, gamma, out);
  k_gemm_out<<<dim3(108, 2, Bn), 256, 0, stream>>>(w2gt, (size_t)128 * 256, xcnbf, b_out2, 128, xnTbf, gamma, out);
}